// Round 1
// baseline (340.751 us; speedup 1.0000x reference)
//
#include <hip/hip_runtime.h>

// PWLU (channelwise piecewise-linear unit), non-learnable bounds ±2.3.
// x: [B=64, C=256, H=56, W=56] fp32; points: [C,7]; left/right_diffs: [C].
// out[i] = false_points[c, r] + (xn - r) * diffs[c, r]
//   xn = (x - sim_left) / region_len,  r = int(clip(xn, 0, 7.007))
// Memory-bound: 411 MB traffic -> target ~65us @ 6.3 TB/s.

constexpr int NP  = 7;        // n_points
constexpr int NT  = 8;        // table entries = n_points + 1
constexpr int CH  = 256;      // channels
constexpr int HW  = 56 * 56;  // 3136 elements per (b,c) plane
constexpr int HW4 = HW / 4;   // 784 float4 per plane

__global__ __launch_bounds__(256) void pwlu_kernel(
    const float4* __restrict__ x,
    const float*  __restrict__ points,
    const float*  __restrict__ left_diffs,
    const float*  __restrict__ right_diffs,
    float4*       __restrict__ out)
{
    __shared__ float2 tbl[NT];   // (false_point, slope) per region

    const int plane = blockIdx.x;        // b*C + c
    const int c     = plane & (CH - 1);  // CH = 256 is a power of 2

    if (threadIdx.x < NT) {
        const int r = threadIdx.x;
        const float* p = points + c * NP;
        float fp, df;
        if (r == 0) {
            const float ld = left_diffs[c];
            fp = p[0] - ld; df = ld;
        } else if (r == NP) {
            fp = p[NP - 1]; df = right_diffs[c];
        } else {
            const float a = p[r - 1], b = p[r];
            fp = a; df = b - a;
        }
        tbl[r] = make_float2(fp, df);
    }
    __syncthreads();

    // Constants derived in float64 then rounded to fp32, matching jax's
    // weak-typed scalar broadcast. (PWLU is continuous at breakpoints, so
    // ulp-level differences in xn are harmless.)
    const float sim_left = -3.0666666666666664f;   // -2.3 - 4.6/6
    const float inv_len  = 1.3043478260869565f;    // 6/4.6
    const float hi       = 7.007f;                  // (n_regions+1)*1.001

    const size_t base = (size_t)plane * HW4;
    for (int j = threadIdx.x; j < HW4; j += 256) {
        const float4 v = x[base + j];
        float4 o;
        {
            const float xn = (v.x - sim_left) * inv_len;
            const int   r  = (int)fminf(fmaxf(xn, 0.0f), hi);
            const float2 t = tbl[r];
            o.x = fmaf(xn - (float)r, t.y, t.x);
        }
        {
            const float xn = (v.y - sim_left) * inv_len;
            const int   r  = (int)fminf(fmaxf(xn, 0.0f), hi);
            const float2 t = tbl[r];
            o.y = fmaf(xn - (float)r, t.y, t.x);
        }
        {
            const float xn = (v.z - sim_left) * inv_len;
            const int   r  = (int)fminf(fmaxf(xn, 0.0f), hi);
            const float2 t = tbl[r];
            o.z = fmaf(xn - (float)r, t.y, t.x);
        }
        {
            const float xn = (v.w - sim_left) * inv_len;
            const int   r  = (int)fminf(fmaxf(xn, 0.0f), hi);
            const float2 t = tbl[r];
            o.w = fmaf(xn - (float)r, t.y, t.x);
        }
        out[base + j] = o;
    }
}

extern "C" void kernel_launch(void* const* d_in, const int* in_sizes, int n_in,
                              void* d_out, int out_size, void* d_ws, size_t ws_size,
                              hipStream_t stream) {
    const float4* x  = (const float4*)d_in[0];
    const float*  pt = (const float*)d_in[1];
    const float*  ld = (const float*)d_in[2];
    const float*  rd = (const float*)d_in[3];
    float4*       o  = (float4*)d_out;

    const int planes = in_sizes[0] / HW;   // B*C = 16384
    pwlu_kernel<<<planes, 256, 0, stream>>>(x, pt, ld, rd, o);
}

// Round 2
// 327.047 us; speedup vs baseline: 1.0419x; 1.0419x over previous
//
#include <hip/hip_runtime.h>

// PWLU (channelwise piecewise-linear unit), non-learnable bounds ±2.3.
// x: [B=64, C=256, H=56, W=56] fp32; points: [C,7]; left/right_diffs: [C].
// out[i] = false_points[c, r] + (xn - r) * diffs[c, r]
//   xn = (x - sim_left) / region_len,  r = int(clip(xn, 0, 7.007))
//
// R1 post-mortem: bench dur_us=340 includes ~246us of harness 0xAA re-poison
// fills (822 MB @ ~123us each, visible in rocprof); kernel itself ~90us vs
// ~65us roofline. R2: full unroll (3 loads + tail in flight), loads issued
// before the LDS table barrier, nontemporal load/store (streaming data,
// no reuse -> don't allocate in L2).

constexpr int NP  = 7;        // n_points
constexpr int NT  = 8;        // table entries = n_points + 1
constexpr int CH  = 256;      // channels
constexpr int HW  = 56 * 56;  // 3136 elements per (b,c) plane
constexpr int HW4 = HW / 4;   // 784 float4 per plane = 3*256 + 16

typedef float f4 __attribute__((ext_vector_type(4)));

__device__ __forceinline__ float pwlu1(float xv, const float2* tbl,
                                       float sim_left, float inv_len, float hi) {
    const float xn = (xv - sim_left) * inv_len;
    const int   r  = (int)fminf(fmaxf(xn, 0.0f), hi);
    const float2 t = tbl[r];
    return fmaf(xn - (float)r, t.y, t.x);
}

__device__ __forceinline__ f4 pwlu4(f4 v, const float2* tbl,
                                    float sim_left, float inv_len, float hi) {
    f4 o;
    o.x = pwlu1(v.x, tbl, sim_left, inv_len, hi);
    o.y = pwlu1(v.y, tbl, sim_left, inv_len, hi);
    o.z = pwlu1(v.z, tbl, sim_left, inv_len, hi);
    o.w = pwlu1(v.w, tbl, sim_left, inv_len, hi);
    return o;
}

__global__ __launch_bounds__(256) void pwlu_kernel(
    const f4* __restrict__ x,
    const float* __restrict__ points,
    const float* __restrict__ left_diffs,
    const float* __restrict__ right_diffs,
    f4* __restrict__ out)
{
    __shared__ float2 tbl[NT];   // (false_point, slope) per region

    const int plane = blockIdx.x;        // b*C + c
    const int c     = plane & (CH - 1);
    const int tid   = threadIdx.x;
    const size_t base = (size_t)plane * HW4;

    // Issue the plane loads first: global latency overlaps table build+barrier.
    const f4* __restrict__ xp = x + base + tid;
    f4 v0 = __builtin_nontemporal_load(xp);
    f4 v1 = __builtin_nontemporal_load(xp + 256);
    f4 v2 = __builtin_nontemporal_load(xp + 512);
    const bool tail = tid < (HW4 - 3 * 256);   // 16 threads
    f4 v3;
    if (tail) v3 = __builtin_nontemporal_load(xp + 768);

    if (tid < NT) {
        const int r = tid;
        const float* p = points + c * NP;
        float fp, df;
        if (r == 0) {
            const float ld = left_diffs[c];
            fp = p[0] - ld; df = ld;
        } else if (r == NP) {
            fp = p[NP - 1]; df = right_diffs[c];
        } else {
            const float a = p[r - 1], b = p[r];
            fp = a; df = b - a;
        }
        tbl[r] = make_float2(fp, df);
    }
    __syncthreads();

    const float sim_left = -3.0666666666666664f;   // -2.3 - 4.6/6
    const float inv_len  = 1.3043478260869565f;    // 6/4.6
    const float hi       = 7.007f;                  // (n_regions+1)*1.001

    f4* __restrict__ op = out + base + tid;
    __builtin_nontemporal_store(pwlu4(v0, tbl, sim_left, inv_len, hi), op);
    __builtin_nontemporal_store(pwlu4(v1, tbl, sim_left, inv_len, hi), op + 256);
    __builtin_nontemporal_store(pwlu4(v2, tbl, sim_left, inv_len, hi), op + 512);
    if (tail)
        __builtin_nontemporal_store(pwlu4(v3, tbl, sim_left, inv_len, hi), op + 768);
}

extern "C" void kernel_launch(void* const* d_in, const int* in_sizes, int n_in,
                              void* d_out, int out_size, void* d_ws, size_t ws_size,
                              hipStream_t stream) {
    const f4*    x  = (const f4*)d_in[0];
    const float* pt = (const float*)d_in[1];
    const float* ld = (const float*)d_in[2];
    const float* rd = (const float*)d_in[3];
    f4*          o  = (f4*)d_out;

    const int planes = in_sizes[0] / HW;   // B*C = 16384
    pwlu_kernel<<<planes, 256, 0, stream>>>(x, pt, ld, rd, o);
}